// Round 7
// baseline (279.766 us; speedup 1.0000x reference)
//
#include <hip/hip_runtime.h>
#include <math.h>

#define RDIM 8192   // B*S
#define DDIM 1024   // 2*L
#define NDIM 8192
#define LDIM 512
#define KT 16       // K-tiles of 64 over K=1024

#define OFF_REAL 0
#define OFF_IMAG 4194304
#define OFF_SAL  8388608
#define OFF_CONF 8396800
#define OFF_LOSS 8404992
#define OFF_IDX  8404993

#define MAXCAND 64
#define MARGIN_Q 76        // 1.1875 units of d: 0.8 bias range + bf16 pair err + quant
#define QSCALE 64.0f
#define FLT_BIG 3.4e38f

typedef __attribute__((ext_vector_type(8))) short bf16x8;
typedef __attribute__((ext_vector_type(8))) short short8v;
typedef __attribute__((ext_vector_type(4))) float f32x4;

__device__ __forceinline__ unsigned short f2bf(float x) {
  unsigned u = __builtin_bit_cast(unsigned, x);
  unsigned r = (u + 0x7fff + ((u >> 16) & 1)) >> 16;
  return (unsigned short)r;
}

__device__ __forceinline__ void load_lds16(const void* g, void* l) {
  __builtin_amdgcn_global_load_lds((const __attribute__((address_space(1))) void*)g,
                                   (__attribute__((address_space(3))) void*)l, 16, 0, 0);
}

__device__ __forceinline__ short clampq(float s) {
  int qi = __float2int_rn(s * QSCALE);
  qi = qi > 32767 ? 32767 : (qi < -32767 ? -32767 : qi);
  return (short)qi;
}

// ============ bf16 cast + exact fp32 norms ============
__global__ __launch_bounds__(256)
void split_norms_kernel(const float* __restrict__ gw_real, const float* __restrict__ gw_imag,
                        const float* __restrict__ codebook,
                        unsigned short* __restrict__ zh, unsigned short* __restrict__ ch,
                        float* __restrict__ znorm, float* __restrict__ cnorm) {
  const int id = blockIdx.x;   // [0, 16384)
  const int t = threadIdx.x;   // 256
  float4 v;
  unsigned short* dst;
  if (id < RDIM) {
    v = (t < 128) ? reinterpret_cast<const float4*>(gw_real + (size_t)id * LDIM)[t]
                  : reinterpret_cast<const float4*>(gw_imag + (size_t)id * LDIM)[t - 128];
    dst = zh;
  } else {
    v = reinterpret_cast<const float4*>(codebook + (size_t)(id - RDIM) * DDIM)[t];
    dst = ch;
  }
  const size_t off = (size_t)(id < RDIM ? id : id - RDIM) * DDIM + t * 4;
  *reinterpret_cast<ushort4*>(dst + off) =
      make_ushort4(f2bf(v.x), f2bf(v.y), f2bf(v.z), f2bf(v.w));
  float s = v.x*v.x + v.y*v.y + v.z*v.z + v.w*v.w;
  __shared__ float red[256];
  red[t] = s;
  __syncthreads();
  for (int st = 128; st > 0; st >>= 1) {
    if (t < st) red[t] += red[t + st];
    __syncthreads();
  }
  if (t == 0) {
    if (id < RDIM) znorm[id] = red[0];
    else           cnorm[id - RDIM] = red[0];
  }
}

// ============ 256x256 tile, BK=64, 8-wave 4-phase bf16 GEMM -> quantized int16 scores ============
// Read-ahead schedule: P1 reads cfA+zfA+cfB (Q1 waits only cfA+zfA); P2 MFMAs Q2 then reads
// zfB (WAR on zf forces order, overlaps into P3); P3/P4 MFMA with zero ds_reads.
#define STAGE(basep, kt, ldsbyte) do {                                        \
    load_lds16((basep) + eo1 + (kt) * 64, L + (ldsbyte) + wid * 1024);        \
    load_lds16((basep) + eo2 + (kt) * 64, L + (ldsbyte) + 8192 + wid * 1024); \
  } while (0)

__global__ __launch_bounds__(512)
void dist_mfma_kernel(const unsigned short* __restrict__ zh, const unsigned short* __restrict__ ch,
                      const float* __restrict__ cnorm, short* __restrict__ q) {
  __shared__ unsigned short ldsbuf[65536];   // 128 KB: [buf][A 32K | B 32K]
  char* const L = (char*)ldsbuf;

  // XCD-aware swizzle (1024 blocks = 8 XCDs x 128, bijective)
  const int sidx = (int)blockIdx.x;
  const int sw = (sidx & 7) * 128 + (sidx >> 3);
  const int bm = sw >> 5, bn = sw & 31;
  const int row0 = bm * 256, col0 = bn * 256;

  const int tid = threadIdx.x;
  const int wid = tid >> 6, l = tid & 63;
  const int wm = wid >> 2, wn = wid & 3;       // 2 x 4 wave grid
  const int lr = l & 15, lg = l >> 4;

  // ---- staging geometry: half-tile = 128 rows x 64 cols bf16 = 1024 chunks of 16B
  const int p1 = tid, p2 = tid + 512;
  const int r1 = p1 >> 3, c1 = (p1 & 7) ^ (r1 & 7);
  const int r2 = p2 >> 3, c2 = (p2 & 7) ^ (r2 & 7);
  const int eo1 = r1 * DDIM + c1 * 8;
  const int eo2 = r2 * DDIM + c2 * 8;
  const unsigned short* const az0 = zh + (size_t)row0 * DDIM;
  const unsigned short* const az1 = zh + (size_t)(row0 + 128) * DDIM;
  const unsigned short* const ac0 = ch + (size_t)col0 * DDIM;
  const unsigned short* const ac1 = ch + (size_t)(col0 + 128) * DDIM;

  // ---- fragment read offsets (row = base + lr, chunk' = (kh*4+lg) ^ (lr&7))
  const int fo0 = lr * 128 + ((lg ^ (lr & 7)) << 4);
  const int fo1 = fo0 ^ 64;

  f32x4 acc[4][8];
#pragma unroll
  for (int i = 0; i < 4; ++i)
#pragma unroll
    for (int j = 0; j < 8; ++j)
      acc[i][j] = (f32x4){0.f, 0.f, 0.f, 0.f};

  bf16x8 cfA[2][2], cfB[2][2], zf[4][2];

  // ---- prologue: tile0 (A+B) into buf0, B(1) into buf1; A(1) staged inside loop t=0
  STAGE(az0, 0, 0);
  STAGE(az1, 0, 16384);
  STAGE(ac0, 0, 32768);
  STAGE(ac1, 0, 49152);
  STAGE(ac0, 1, 98304);
  STAGE(ac1, 1, 114688);
  asm volatile("s_waitcnt vmcnt(4)" ::: "memory");   // tile0 landed; B(1) may fly
  __builtin_amdgcn_sched_barrier(0);
  __builtin_amdgcn_s_barrier();

  for (int t = 0; t < KT; ++t) {
    const int buf = t & 1, nbuf = buf ^ 1;
    const char* const Ab = L + buf * 65536 + wm * 16384;          // wave's z-half
    const char* const Bb = L + buf * 65536 + 32768 + wn * 8192;   // wave's c-64-block

    // ======== P1: read cfA+zfA (Q1 operands) then cfB (Q2, overlaps); stage A0(t+1) ========
#pragma unroll
    for (int i = 0; i < 2; ++i) {
      cfA[i][0] = *reinterpret_cast<const bf16x8*>(Bb + i * 2048 + fo0);
      cfA[i][1] = *reinterpret_cast<const bf16x8*>(Bb + i * 2048 + fo1);
    }
#pragma unroll
    for (int j = 0; j < 4; ++j) {
      zf[j][0] = *reinterpret_cast<const bf16x8*>(Ab + j * 2048 + fo0);
      zf[j][1] = *reinterpret_cast<const bf16x8*>(Ab + j * 2048 + fo1);
    }
#pragma unroll
    for (int i = 0; i < 2; ++i) {
      cfB[i][0] = *reinterpret_cast<const bf16x8*>(Bb + (2 + i) * 2048 + fo0);
      cfB[i][1] = *reinterpret_cast<const bf16x8*>(Bb + (2 + i) * 2048 + fo1);
    }
    if (t + 1 < KT) STAGE(az0, t + 1, nbuf * 65536);
    __builtin_amdgcn_sched_barrier(0);
    __builtin_amdgcn_s_barrier();
    __builtin_amdgcn_s_setprio(1);
#pragma unroll
    for (int kh = 0; kh < 2; ++kh)
#pragma unroll
      for (int i = 0; i < 2; ++i)
#pragma unroll
        for (int j = 0; j < 4; ++j)
          acc[i][j] = __builtin_amdgcn_mfma_f32_16x16x32_bf16(cfA[i][kh], zf[j][kh], acc[i][j], 0, 0, 0);
    __builtin_amdgcn_s_setprio(0);
    __builtin_amdgcn_sched_barrier(0);
    __builtin_amdgcn_s_barrier();

    // ======== P2: stage A1(t+1); MFMA Q2 (cfB x zfA); then read zfB for P3 ========
    if (t + 1 < KT) STAGE(az1, t + 1, nbuf * 65536 + 16384);
    __builtin_amdgcn_sched_barrier(0);
    __builtin_amdgcn_s_barrier();
    __builtin_amdgcn_s_setprio(1);
#pragma unroll
    for (int kh = 0; kh < 2; ++kh)
#pragma unroll
      for (int i = 0; i < 2; ++i)
#pragma unroll
        for (int j = 0; j < 4; ++j)
          acc[2 + i][j] = __builtin_amdgcn_mfma_f32_16x16x32_bf16(cfB[i][kh], zf[j][kh], acc[2 + i][j], 0, 0, 0);
    __builtin_amdgcn_s_setprio(0);
#pragma unroll
    for (int j = 0; j < 4; ++j) {           // zfB: WAR on zf keeps these after Q2's MFMAs
      zf[j][0] = *reinterpret_cast<const bf16x8*>(Ab + (4 + j) * 2048 + fo0);
      zf[j][1] = *reinterpret_cast<const bf16x8*>(Ab + (4 + j) * 2048 + fo1);
    }
    __builtin_amdgcn_sched_barrier(0);
    __builtin_amdgcn_s_barrier();

    // ======== P3: stage B0(t+2) into current buf (B reads all retired); MFMA Q3 ========
    if (t + 2 < KT) STAGE(ac0, t + 2, buf * 65536 + 32768);
    __builtin_amdgcn_sched_barrier(0);
    __builtin_amdgcn_s_barrier();
    __builtin_amdgcn_s_setprio(1);
#pragma unroll
    for (int kh = 0; kh < 2; ++kh)
#pragma unroll
      for (int i = 0; i < 2; ++i)
#pragma unroll
        for (int j = 0; j < 4; ++j)
          acc[2 + i][4 + j] = __builtin_amdgcn_mfma_f32_16x16x32_bf16(cfB[i][kh], zf[j][kh], acc[2 + i][4 + j], 0, 0, 0);
    __builtin_amdgcn_s_setprio(0);
    __builtin_amdgcn_sched_barrier(0);
    __builtin_amdgcn_s_barrier();

    // ======== P4: stage B1(t+2); counted vmcnt; MFMA Q4 (all operands in regs) ========
    if (t + 2 < KT) STAGE(ac1, t + 2, buf * 65536 + 49152);
    if (t < KT - 2) { asm volatile("s_waitcnt vmcnt(4)" ::: "memory"); }
    else            { asm volatile("s_waitcnt vmcnt(0)" ::: "memory"); }
    __builtin_amdgcn_sched_barrier(0);
    __builtin_amdgcn_s_barrier();
    __builtin_amdgcn_s_setprio(1);
#pragma unroll
    for (int kh = 0; kh < 2; ++kh)
#pragma unroll
      for (int i = 0; i < 2; ++i)
#pragma unroll
        for (int j = 0; j < 4; ++j)
          acc[i][4 + j] = __builtin_amdgcn_mfma_f32_16x16x32_bf16(cfA[i][kh], zf[j][kh], acc[i][4 + j], 0, 0, 0);
    __builtin_amdgcn_s_setprio(0);
    __builtin_amdgcn_sched_barrier(0);
    __builtin_amdgcn_s_barrier();
  }

  // ---- epilogue: s = cn - 2*dot, quantize, nontemporal 8B stores (keep zh/ch in L2/L3)
  const int czero = col0 + wn * 64;
  const int zzero = row0 + wm * 128;
#pragma unroll
  for (int i = 0; i < 4; ++i) {
    const int cc = czero + i * 16 + lg * 4;
    const float4 cn4 = *reinterpret_cast<const float4*>(cnorm + cc);
#pragma unroll
    for (int j = 0; j < 8; ++j) {
      const int zr = zzero + j * 16 + lr;
      const f32x4 a = acc[i][j];
      const short4 s4 = make_short4(clampq(cn4.x - 2.0f * a[0]), clampq(cn4.y - 2.0f * a[1]),
                                    clampq(cn4.z - 2.0f * a[2]), clampq(cn4.w - 2.0f * a[3]));
      __builtin_nontemporal_store(__builtin_bit_cast(long long, s4),
          reinterpret_cast<long long*>(q + (size_t)zr * NDIM + cc));
    }
  }
}

// ============ streaming per-row min + candidate collection ============
__global__ __launch_bounds__(256)
void collect_kernel(const short* __restrict__ q, const int* __restrict__ prev,
                    const float* __restrict__ adj, const float* __restrict__ znorm,
                    float* __restrict__ out, float* __restrict__ minfinal,
                    int* __restrict__ idxfinal,
                    int* __restrict__ gcount, int* __restrict__ gcand) {
  __shared__ unsigned s_wmin[4];
  __shared__ int s_cnt;
  __shared__ int s_list[MAXCAND];
  const int row = blockIdx.x;
  const int t = threadIdx.x;    // 256
  if (t == 0) s_cnt = 0;
  short8v v[4];
  unsigned kmin = 0xffffffffu;
#pragma unroll
  for (int c = 0; c < 4; ++c) {
    v[c] = *reinterpret_cast<const short8v*>(q + (size_t)row * NDIM + (c * 256 + t) * 8);
#pragma unroll
    for (int j = 0; j < 8; ++j) {
      const int col = (c * 256 + t) * 8 + j;
      const unsigned key = (((unsigned)((int)v[c][j] + 32768)) << 13) | (unsigned)col;
      kmin = (key < kmin) ? key : kmin;     // lex (q, col) min
    }
  }
  for (int m = 1; m < 64; m <<= 1) {
    const unsigned o = (unsigned)__shfl_xor((int)kmin, m, 64);
    kmin = (o < kmin) ? o : kmin;
  }
  if ((t & 63) == 0) s_wmin[t >> 6] = kmin;
  __syncthreads();
  unsigned gk = s_wmin[0];
  gk = gk < s_wmin[1] ? gk : s_wmin[1];
  gk = gk < s_wmin[2] ? gk : s_wmin[2];
  gk = gk < s_wmin[3] ? gk : s_wmin[3];
  const int qmin = (int)(gk >> 13) - 32768;
  const int winner = (int)(gk & 8191u);
  const int thr = qmin + MARGIN_Q;
#pragma unroll
  for (int c = 0; c < 4; ++c) {
#pragma unroll
    for (int j = 0; j < 8; ++j) {
      if ((int)v[c][j] <= thr) {
        const int pos = atomicAdd(&s_cnt, 1);
        if (pos < MAXCAND) s_list[pos] = (c * 256 + t) * 8 + j;
      }
    }
  }
  __syncthreads();
  const int cnt = (s_cnt < MAXCAND) ? s_cnt : MAXCAND;
  if (t == 0) {
    gcount[row] = (cnt <= 1) ? 1 : cnt;
    out[OFF_IDX + row] = (float)winner;
    idxfinal[row] = winner;
    if (cnt <= 1) {
      const int p = prev[row];
      const float bias = 0.8f / (1.0f + expf(-adj[(size_t)p * NDIM + winner]));
      minfinal[row] = znorm[row] + (float)qmin * (1.0f / QSCALE) - bias;
    } else {
      minfinal[row] = znorm[row] + (float)qmin * (1.0f / QSCALE);  // refine overwrites
    }
  }
  if (cnt > 1 && t < cnt) gcand[(size_t)row * MAXCAND + t] = s_list[t];
}

// ============ exact fp32 refine of ambiguous rows (biased lex-min over candidates) ============
__global__ __launch_bounds__(64)
void refine_kernel(const float* __restrict__ gw_real, const float* __restrict__ gw_imag,
                   const float* __restrict__ codebook, const int* __restrict__ prev,
                   const float* __restrict__ adj, const float* __restrict__ znorm,
                   const float* __restrict__ cnorm,
                   const int* __restrict__ gcount, const int* __restrict__ gcand,
                   float* __restrict__ out, float* __restrict__ minfinal,
                   int* __restrict__ idxfinal) {
  const int row = blockIdx.x;
  const int t = threadIdx.x;   // 64 lanes, 16 contiguous floats each
  const int K = gcount[row];
  if (K <= 1) return;
  const int base = t * 16;
  const float* zp = (base < LDIM) ? gw_real + (size_t)row * LDIM + base
                                  : gw_imag + (size_t)row * LDIM + (base - LDIM);
  float z[16];
#pragma unroll
  for (int c = 0; c < 4; ++c) {
    const float4 v = reinterpret_cast<const float4*>(zp)[c];
    z[c*4+0] = v.x; z[c*4+1] = v.y; z[c*4+2] = v.z; z[c*4+3] = v.w;
  }
  const float zn = znorm[row];
  const int p = prev[row];
  float bestd = FLT_BIG;
  int besti = 0x7fffffff;
  for (int j = 0; j < K; ++j) {
    const int idx = gcand[(size_t)row * MAXCAND + j];
    const float* cp = codebook + (size_t)idx * DDIM + base;
    float dot = 0.f;
#pragma unroll
    for (int c = 0; c < 4; ++c) {
      const float4 v = reinterpret_cast<const float4*>(cp)[c];
      dot += z[c*4+0]*v.x + z[c*4+1]*v.y + z[c*4+2]*v.z + z[c*4+3]*v.w;
    }
    for (int m = 1; m < 64; m <<= 1) dot += __shfl_xor(dot, m, 64);
    const float d = zn + cnorm[idx] - 2.0f * dot
                  - 0.8f / (1.0f + expf(-adj[(size_t)p * NDIM + idx]));
    if (d < bestd || (d == bestd && idx < besti)) { bestd = d; besti = idx; }
  }
  if (t == 0) {
    out[OFF_IDX + row] = (float)besti;
    minfinal[row] = bestd;
    idxfinal[row] = besti;
  }
}

// ============ SHARED EPILOGUE ============

__global__ __launch_bounds__(256)
void epilogue_kernel(const float* __restrict__ gw_real, const float* __restrict__ gw_imag,
                     const float* __restrict__ codebook,
                     const float* __restrict__ sal_w, const float* __restrict__ sal_b,
                     const float* __restrict__ conf_w, const float* __restrict__ conf_b,
                     const float* __restrict__ minfinal, const int* __restrict__ idxfinal,
                     float* __restrict__ out, float* __restrict__ rowloss) {
  const int row = blockIdx.x;
  const int t = threadIdx.x;
  const int k = t << 2;
  const int idx = idxfinal[row];
  const float4 qv = *reinterpret_cast<const float4*>(codebook + (size_t)idx * DDIM + k);
  float4 z;
  if (k < LDIM) z = *reinterpret_cast<const float4*>(gw_real + (size_t)row * LDIM + k);
  else          z = *reinterpret_cast<const float4*>(gw_imag + (size_t)row * LDIM + (k - LDIM));
  const float dx = qv.x - z.x, dy = qv.y - z.y, dz = qv.z - z.z, dw = qv.w - z.w;
  float4 st;
  st.x = z.x + dx; st.y = z.y + dy; st.z = z.z + dz; st.w = z.w + dw;
  float* dst = (k < LDIM) ? (out + OFF_REAL + (size_t)row * LDIM + k)
                          : (out + OFF_IMAG + (size_t)row * LDIM + (k - LDIM));
  *reinterpret_cast<float4*>(dst) = st;
  const float4 sw = *reinterpret_cast<const float4*>(sal_w + k);
  const float4 cw = *reinterpret_cast<const float4*>(conf_w + k);
  const float sdot = st.x*sw.x + st.y*sw.y + st.z*sw.z + st.w*sw.w;
  const float cdot = st.x*cw.x + st.y*cw.y + st.z*cw.z + st.w*cw.w;
  const float dif = dx*dx + dy*dy + dz*dz + dw*dw;
  __shared__ float r1[256], r2[256], r3[256];
  r1[t] = sdot; r2[t] = cdot; r3[t] = dif;
  __syncthreads();
  for (int s = 128; s > 0; s >>= 1) {
    if (t < s) { r1[t] += r1[t + s]; r2[t] += r2[t + s]; r3[t] += r3[t + s]; }
    __syncthreads();
  }
  if (t == 0) {
    out[OFF_SAL + row]  = r1[0] + sal_b[0] + 0.1f * (-minfinal[row]);
    out[OFF_CONF + row] = 1.0f / (1.0f + expf(-(r2[0] + conf_b[0])));
    rowloss[row] = r3[0];
  }
}

__global__ __launch_bounds__(256)
void loss_kernel(const float* __restrict__ rowloss, float* __restrict__ out) {
  const int t = threadIdx.x;
  float s = 0.f;
  for (int i = t; i < RDIM; i += 256) s += rowloss[i];
  __shared__ float red[256];
  red[t] = s;
  __syncthreads();
  for (int st = 128; st > 0; st >>= 1) {
    if (t < st) red[t] += red[t + st];
    __syncthreads();
  }
  if (t == 0) {
    const float m = red[0] / (float)((size_t)RDIM * DDIM);
    out[OFF_LOSS] = m + 0.01f * m;
  }
}

// ============ FALLBACK (round-1 fp32 path) ============

__global__ __launch_bounds__(256)
void norms_kernel(const float* __restrict__ gw_real, const float* __restrict__ gw_imag,
                  const float* __restrict__ codebook,
                  float* __restrict__ znorm, float* __restrict__ cnorm) {
  const int id = blockIdx.x;
  const int t = threadIdx.x;
  float s;
  if (id < RDIM) {
    const float4* zr = reinterpret_cast<const float4*>(gw_real + (size_t)id * LDIM);
    const float4* zi = reinterpret_cast<const float4*>(gw_imag + (size_t)id * LDIM);
    const float4 v = (t < 128) ? zr[t] : zi[t - 128];
    s = v.x*v.x + v.y*v.y + v.z*v.z + v.w*v.w;
  } else {
    const float4* c = reinterpret_cast<const float4*>(codebook + (size_t)(id - RDIM) * DDIM);
    const float4 v = c[t];
    s = v.x*v.x + v.y*v.y + v.z*v.z + v.w*v.w;
  }
  __shared__ float red[256];
  red[t] = s;
  __syncthreads();
  for (int st = 128; st > 0; st >>= 1) {
    if (t < st) red[t] += red[t + st];
    __syncthreads();
  }
  if (t == 0) {
    if (id < RDIM) znorm[id] = red[0];
    else           cnorm[id - RDIM] = red[0];
  }
}

__global__ __launch_bounds__(256)
void dist_kernel(const float* __restrict__ gw_real, const float* __restrict__ gw_imag,
                 const float* __restrict__ codebook, const int* __restrict__ prev,
                 const float* __restrict__ adj, const float* __restrict__ znorm,
                 const float* __restrict__ cnorm,
                 float* __restrict__ ws_min, int* __restrict__ ws_idx) {
  __shared__ float As[16][64];
  __shared__ float Bs[16][64];
  __shared__ int prevs[64];
  const int bm = blockIdx.x, bn = blockIdx.y;
  const int row0 = bm * 64, col0 = bn * 64;
  const int tid = threadIdx.x;
  const int tx = tid & 15, ty = tid >> 4;
  if (tid < 64) prevs[tid] = prev[row0 + tid];
  const int lm = tid >> 2;
  const int lk = (tid & 3) << 2;
  const int arow = row0 + lm;
  const int brow = col0 + lm;
  float acc[4][4] = {{0.f,0.f,0.f,0.f},{0.f,0.f,0.f,0.f},{0.f,0.f,0.f,0.f},{0.f,0.f,0.f,0.f}};
  for (int kk = 0; kk < DDIM; kk += 16) {
    const int k = kk + lk;
    float4 a, b;
    if (k < LDIM) a = *reinterpret_cast<const float4*>(gw_real + (size_t)arow * LDIM + k);
    else          a = *reinterpret_cast<const float4*>(gw_imag + (size_t)arow * LDIM + (k - LDIM));
    b = *reinterpret_cast<const float4*>(codebook + (size_t)brow * DDIM + k);
    __syncthreads();
    As[lk+0][lm]=a.x; As[lk+1][lm]=a.y; As[lk+2][lm]=a.z; As[lk+3][lm]=a.w;
    Bs[lk+0][lm]=b.x; Bs[lk+1][lm]=b.y; Bs[lk+2][lm]=b.z; Bs[lk+3][lm]=b.w;
    __syncthreads();
#pragma unroll
    for (int k2 = 0; k2 < 16; ++k2) {
      const float4 a4 = *reinterpret_cast<const float4*>(&As[k2][ty << 2]);
      const float4 b4 = *reinterpret_cast<const float4*>(&Bs[k2][tx << 2]);
      const float av[4] = {a4.x, a4.y, a4.z, a4.w};
      const float bv[4] = {b4.x, b4.y, b4.z, b4.w};
#pragma unroll
      for (int i = 0; i < 4; ++i)
#pragma unroll
        for (int j = 0; j < 4; ++j)
          acc[i][j] = fmaf(av[i], bv[j], acc[i][j]);
    }
  }
  const float4 cn4 = *reinterpret_cast<const float4*>(cnorm + col0 + (tx << 2));
  const float cnv[4] = {cn4.x, cn4.y, cn4.z, cn4.w};
#pragma unroll
  for (int i = 0; i < 4; ++i) {
    const int rsub = (ty << 2) + i;
    const int row = row0 + rsub;
    const float zn = znorm[row];
    const int p = prevs[rsub];
    const float4 ad4 = *reinterpret_cast<const float4*>(adj + (size_t)p * NDIM + col0 + (tx << 2));
    const float adv[4] = {ad4.x, ad4.y, ad4.z, ad4.w};
    float bv = FLT_BIG;
    int bi = -1;
#pragma unroll
    for (int j = 0; j < 4; ++j) {
      const float bias = 0.8f * (1.0f / (1.0f + expf(-adv[j])));
      const float dv = (zn + cnv[j]) - 2.0f * acc[i][j] - bias;
      const int col = col0 + (tx << 2) + j;
      if (dv < bv) { bv = dv; bi = col; }
    }
    for (int m = 1; m < 16; m <<= 1) {
      const float ov = __shfl_xor(bv, m, 64);
      const int   oi = __shfl_xor(bi, m, 64);
      if (ov < bv || (ov == bv && oi < bi)) { bv = ov; bi = oi; }
    }
    if (tx == 0) {
      ws_min[(size_t)row * 128 + bn] = bv;
      ws_idx[(size_t)row * 128 + bn] = bi;
    }
  }
}

__global__ __launch_bounds__(128)
void argmin_reduce(const float* __restrict__ ws_min, const int* __restrict__ ws_idx,
                   float* __restrict__ out, float* __restrict__ minfinal,
                   int* __restrict__ idxfinal) {
  const int row = blockIdx.x;
  const int t = threadIdx.x;
  __shared__ float sv[128];
  __shared__ int   si[128];
  sv[t] = ws_min[(size_t)row * 128 + t];
  si[t] = ws_idx[(size_t)row * 128 + t];
  __syncthreads();
  for (int s = 64; s > 0; s >>= 1) {
    if (t < s) {
      const float ov = sv[t + s];
      const int   oi = si[t + s];
      if (ov < sv[t] || (ov == sv[t] && oi < si[t])) { sv[t] = ov; si[t] = oi; }
    }
    __syncthreads();
  }
  if (t == 0) {
    out[OFF_IDX + row] = (float)si[0];
    minfinal[row] = sv[0];
    idxfinal[row] = si[0];
  }
}

// ============ HOST ============

extern "C" void kernel_launch(void* const* d_in, const int* in_sizes, int n_in,
                              void* d_out, int out_size, void* d_ws, size_t ws_size,
                              hipStream_t stream) {
  const float* gw_real  = (const float*)d_in[0];
  const float* gw_imag  = (const float*)d_in[1];
  const int*   prev     = (const int*)d_in[2];
  const float* codebook = (const float*)d_in[3];
  const float* adj      = (const float*)d_in[4];
  const float* sal_w    = (const float*)d_in[5];
  const float* sal_b    = (const float*)d_in[6];
  const float* conf_w   = (const float*)d_in[7];
  const float* conf_b   = (const float*)d_in[8];
  float* out = (float*)d_out;
  char* ws = (char*)d_ws;

  const size_t matsz = (size_t)RDIM * DDIM;              // bf16 elements per matrix
  const size_t qsz   = (size_t)RDIM * NDIM;              // int16 score matrix
  size_t need = 2 * matsz * 2                            // zh, ch (bf16)
              + qsz * 2                                  // q (int16)
              + (size_t)RDIM * MAXCAND * 4               // gcand
              + 6 * (size_t)RDIM * 4 + 4096;             // gcount,znorm,cnorm,minfinal,idxfinal,rowloss

  if (ws_size >= need) {
    unsigned short* zh = (unsigned short*)ws;
    unsigned short* chh = zh + matsz;
    short* q = (short*)(chh + matsz);
    int*   gcand  = (int*)(q + qsz);
    int*   gcount = gcand + (size_t)RDIM * MAXCAND;
    float* znorm    = (float*)(gcount + RDIM);
    float* cnorm    = znorm + RDIM;
    float* minfinal = cnorm + NDIM;
    int*   idxfinal = (int*)(minfinal + RDIM);
    float* rowloss  = (float*)(idxfinal + RDIM);

    split_norms_kernel<<<RDIM + NDIM, 256, 0, stream>>>(gw_real, gw_imag, codebook,
                                                        zh, chh, znorm, cnorm);
    dist_mfma_kernel<<<1024, 512, 0, stream>>>(zh, chh, cnorm, q);
    collect_kernel<<<RDIM, 256, 0, stream>>>(q, prev, adj, znorm,
                                             out, minfinal, idxfinal, gcount, gcand);
    refine_kernel<<<RDIM, 64, 0, stream>>>(gw_real, gw_imag, codebook, prev, adj,
                                           znorm, cnorm, gcount, gcand,
                                           out, minfinal, idxfinal);
    epilogue_kernel<<<RDIM, 256, 0, stream>>>(gw_real, gw_imag, codebook, sal_w, sal_b,
                                              conf_w, conf_b, minfinal, idxfinal, out, rowloss);
    loss_kernel<<<1, 256, 0, stream>>>(rowloss, out);
  } else {
    float* ws_min   = (float*)ws;
    int*   ws_idx   = (int*)(ws + (size_t)RDIM * 128 * 4);
    float* znorm    = (float*)(ws + (size_t)RDIM * 128 * 8);
    float* cnorm    = znorm + RDIM;
    float* minfinal = cnorm + NDIM;
    int*   idxfinal = (int*)(minfinal + RDIM);
    float* rowloss  = (float*)(idxfinal + RDIM);

    norms_kernel<<<RDIM + NDIM, 256, 0, stream>>>(gw_real, gw_imag, codebook, znorm, cnorm);
    dist_kernel<<<dim3(RDIM / 64, NDIM / 64), 256, 0, stream>>>(
        gw_real, gw_imag, codebook, prev, adj, znorm, cnorm, ws_min, ws_idx);
    argmin_reduce<<<RDIM, 128, 0, stream>>>(ws_min, ws_idx, out, minfinal, idxfinal);
    epilogue_kernel<<<RDIM, 256, 0, stream>>>(gw_real, gw_imag, codebook, sal_w, sal_b,
                                              conf_w, conf_b, minfinal, idxfinal, out, rowloss);
    loss_kernel<<<1, 256, 0, stream>>>(rowloss, out);
  }
}